// Round 6
// baseline (450.514 us; speedup 1.0000x reference)
//
#include <hip/hip_runtime.h>

// R13: gates into the MFMA M-dimension. R9b wasted 75% of each MFMA on
// 4x-row-replication (12 MFMA/wave for 4 seqs, 1 wave/SIMD -> ~420 cyc
// exposed latency). Now: A = W^T tile, M-row m = 4*u_local + gate (16 rows
// = 4 units x 4 gates); B = [h|x] with N = 16 DISTINCT sequences. C layout
// (col=l&15, row=4(l>>4)+reg) => lane l holds all 4 gates of cell
// (seq=l&15, unit=4w+(l>>4)) in its 4 regs: no replication, no shuffles.
// Block = 16 seqs, 1024 thr, 16 waves, 3 MFMA/wave; per SIMD 4 waves x 3 =
// 12 MFMA (same pipe time as R9b) but 4 co-resident waves overlap each
// other's ds_read/ACT/barrier latencies (m114). x never touches LDS: fp16
// embedding table (3.2 MB, d_ws, built once) -> per-lane dwordx4 load of
// the B-chunk2 fragment, prefetched 2 steps ahead; lgkm-only barriers keep
// the loads in flight. LDS h rows padded to 144 B (balanced 8-class banks
// for the 16-row b128 reads). 32 blocks; wall = step-chain x 512 -- device
// utilization is irrelevant, only chain length matters.

#define VOCAB 50000
#define EMB 32
#define HID 64
#define NCLS 3
#define BATCH 512
#define TSEQ 512
#define FOURH 256
#define LOG2E 1.4426950408889634f
#define GSEQ 16
#define NBLK (BATCH / GSEQ)     // 32
#define ROWB 144                // bytes per h-row (64 halves + 8 pad)
#define BUFB (GSEQ * ROWB)      // 2304 B per buffer

typedef _Float16 half8 __attribute__((ext_vector_type(8)));
typedef float f32x4 __attribute__((ext_vector_type(4)));

#define MFMA16 __builtin_amdgcn_mfma_f32_16x16x32_f16
#define PKRTZ(a, b) __builtin_bit_cast(int, __builtin_amdgcn_cvt_pkrtz((a), (b)))

// LDS writes drained for cross-wave visibility; global loads stay in flight.
#define WAVE_BARRIER()                                        \
    {                                                         \
        asm volatile("s_waitcnt lgkmcnt(0)" ::: "memory");    \
        __builtin_amdgcn_s_barrier();                         \
    }

__global__ __launch_bounds__(256)
void build_emb16(const float* __restrict__ emb, _Float16* __restrict__ emb16) {
    const int idx = blockIdx.x * 256 + threadIdx.x;
    if (idx >= (VOCAB * EMB) / 8) return;
    const float4* src = (const float4*)(emb + (long)idx * 8);
    const float4 a = src[0], b = src[1];
    int4 o;
    o.x = PKRTZ(a.x, a.y);
    o.y = PKRTZ(a.z, a.w);
    o.z = PKRTZ(b.x, b.y);
    o.w = PKRTZ(b.z, b.w);
    ((int4*)emb16)[idx] = o;
}

// One step. CUR = buffer parity, TT = timestep. XR holds x(TT) (consumed,
// then reloaded with x(TT+2) via TKR = token(TT+2)); TKR refilled to
// token(TT+4).
#define LSTM_STEP(CUR, TT, XR, TKR)                                           \
    {                                                                         \
        const half8 b0 = *(const half8*)(hxc + (CUR) * BUFB + bbase);         \
        const half8 b1 = *(const half8*)(hxc + (CUR) * BUFB + bbase + 64);    \
        const half8 xcur = XR;                                                \
        if (TAB) {                                                            \
            XR = *(const half8*)(emb16 + (long)TKR * EMB + (q << 3));         \
        } else {                                                              \
            const float4* xp = (const float4*)(emb + (long)TKR * EMB + (q << 3)); \
            const float4 xa = xp[0], xb = xp[1];                              \
            int4 pk;                                                          \
            pk.x = PKRTZ(xa.x, xa.y);                                         \
            pk.y = PKRTZ(xa.z, xa.w);                                         \
            pk.z = PKRTZ(xb.x, xb.y);                                         \
            pk.w = PKRTZ(xb.z, xb.w);                                         \
            XR = __builtin_bit_cast(half8, pk);                               \
        }                                                                     \
        const int tn4 = ((TT) + 4 < TSEQ) ? (TT) + 4 : TSEQ - 1;              \
        TKR = tokp[tn4];                                                      \
        f32x4 acc;                                                            \
        acc = MFMA16(wf0, b0, zz, 0, 0, 0);                                   \
        acc = MFMA16(wf1, b1, acc, 0, 0, 0);                                  \
        acc = MFMA16(wf2, xcur, acc, 0, 0, 0);                                \
        const float si = __builtin_amdgcn_rcpf(                               \
            1.0f + __builtin_amdgcn_exp2f(fmaf(acc[0], -LOG2E, bci)));        \
        const float sf = __builtin_amdgcn_rcpf(                               \
            1.0f + __builtin_amdgcn_exp2f(fmaf(acc[1], -LOG2E, bcf)));        \
        const float sg = __builtin_amdgcn_rcpf(                               \
            1.0f + __builtin_amdgcn_exp2f(fmaf(acc[2], -2.0f * LOG2E, bcg))); \
        const float so = __builtin_amdgcn_rcpf(                               \
            1.0f + __builtin_amdgcn_exp2f(fmaf(acc[3], -LOG2E, bco)));        \
        const float gt = fmaf(2.0f, sg, -1.0f);                               \
        cst = fmaf(sf, cst, si * gt);                                         \
        const float st2 = __builtin_amdgcn_rcpf(                              \
            1.0f + __builtin_amdgcn_exp2f(cst * (-2.0f * LOG2E)));            \
        const float hv = so * fmaf(2.0f, st2, -1.0f);                         \
        *(_Float16*)(hxc + ((CUR) ^ 1) * BUFB + hwoff) = (_Float16)hv;        \
        WAVE_BARRIER()                                                        \
    }

template <bool TAB>
__global__ __launch_bounds__(1024)
void lstm_kernel(const int* __restrict__ tokens, const float* __restrict__ emb,
                 const float* __restrict__ Wk, const float* __restrict__ Wr,
                 const float* __restrict__ bias, const float* __restrict__ Wd,
                 const float* __restrict__ bd, const _Float16* __restrict__ emb16,
                 float* __restrict__ out)
{
    // [buf][seq]: 64 fp16 h + 8 halves pad per row (144 B).
    __shared__ __align__(16) _Float16 hx[2][GSEQ][ROWB / 2];

    const int tid = threadIdx.x;
    const int w   = tid >> 6;          // wave 0..15 -> units [4w, 4w+4)
    const int l   = tid & 63;
    const int s   = l & 15;            // seq (B-col / C-col); also A-row m
    const int q   = l >> 4;            // k-subchunk; also cell u_local
    const int s0  = blockIdx.x << 4;   // first sequence of this block

    char* hxc = (char*)&hx[0][0][0];

    // ---- zero h-region of buffer 0 (16 rows x 128 B) ----
    if (tid < 128) {
        int4 z4; z4.x = 0; z4.y = 0; z4.z = 0; z4.w = 0;
        *(int4*)(hxc + (tid >> 3) * ROWB + ((tid & 7) << 4)) = z4;
    }

    // ---- weight fragments: A[m][k], m = l&15 -> (u_local = m>>2, gate = m&3),
    //      k = 32c + 8q + i. W col = 64*gate + (4w + u_local).
    //      Rows 0..63 = Wr, 64..95 = Wk. 3 half8 = 12 VGPRs. ----
    half8 wf0, wf1, wf2;
    {
        const int g   = s & 3;
        const int col = (g << 6) + (w << 2) + (s >> 2);
#pragma unroll
        for (int i = 0; i < 8; ++i) {
            const int kq = (q << 3) + i;
            wf0[i] = (_Float16)Wr[kq * FOURH + col];
            wf1[i] = (_Float16)Wr[(32 + kq) * FOURH + col];
            wf2[i] = (_Float16)Wk[kq * FOURH + col];
        }
    }

    // ---- activation constants for this lane's cell (unit u) ----
    const int u = (w << 2) + q;
    const float bci = -bias[u] * LOG2E;
    const float bcf = -bias[u + 64] * LOG2E;
    const float bcg = -bias[u + 128] * (2.0f * LOG2E);
    const float bco = -bias[u + 192] * LOG2E;

    // ---- per-lane LDS byte offsets ----
    const int bbase = s * ROWB + (q << 4);   // B-frag read base (chunk 0)
    const int hwoff = s * ROWB + (u << 1);   // h write: [seq=s][u]

    // ---- x prefetch pipeline: per-lane tokens + fp16 x fragments ----
    const int* tokp = tokens + (long)(s0 + s) * TSEQ;
    int tkA = tokp[0];
    int tkB = tokp[1];
    half8 x0, x1;
    if (TAB) {
        x0 = *(const half8*)(emb16 + (long)tkA * EMB + (q << 3));
        x1 = *(const half8*)(emb16 + (long)tkB * EMB + (q << 3));
    } else {
        const float4* p0 = (const float4*)(emb + (long)tkA * EMB + (q << 3));
        const float4 a0 = p0[0], a1 = p0[1];
        int4 pk;
        pk.x = PKRTZ(a0.x, a0.y); pk.y = PKRTZ(a0.z, a0.w);
        pk.z = PKRTZ(a1.x, a1.y); pk.w = PKRTZ(a1.z, a1.w);
        x0 = __builtin_bit_cast(half8, pk);
        const float4* p1 = (const float4*)(emb + (long)tkB * EMB + (q << 3));
        const float4 b0 = p1[0], b1 = p1[1];
        pk.x = PKRTZ(b0.x, b0.y); pk.y = PKRTZ(b0.z, b0.w);
        pk.z = PKRTZ(b1.x, b1.y); pk.w = PKRTZ(b1.z, b1.w);
        x1 = __builtin_bit_cast(half8, pk);
    }
    tkA = tokp[2];
    tkB = tokp[3];

    __syncthreads();   // zeroed h visible

    float cst = 0.0f;
    const f32x4 zz = {0.0f, 0.0f, 0.0f, 0.0f};

    for (int t = 0; t < TSEQ; t += 2) {
        LSTM_STEP(0, t,     x0, tkA)
        LSTM_STEP(1, t + 1, x1, tkB)
    }

    // ---- epilogue: final h in buf 0. Dense(3) + softmax, one seq/thread ----
    if (tid < GSEQ) {
        const _Float16* hf = (const _Float16*)(hxc + tid * ROWB);
        float a0 = bd[0], a1 = bd[1], a2 = bd[2];
#pragma unroll 8
        for (int k = 0; k < HID; ++k) {
            const float hk = (float)hf[k];
            a0 = fmaf(hk, Wd[k * NCLS + 0], a0);
            a1 = fmaf(hk, Wd[k * NCLS + 1], a1);
            a2 = fmaf(hk, Wd[k * NCLS + 2], a2);
        }
        const float mm = fmaxf(a0, fmaxf(a1, a2));
        const float e0 = __expf(a0 - mm);
        const float e1 = __expf(a1 - mm);
        const float e2 = __expf(a2 - mm);
        const float den = e0 + e1 + e2;
        float* op = out + (s0 + tid) * NCLS;
        op[0] = e0 / den;
        op[1] = e1 / den;
        op[2] = e2 / den;
    }
}

extern "C" void kernel_launch(void* const* d_in, const int* in_sizes, int n_in,
                              void* d_out, int out_size, void* d_ws, size_t ws_size,
                              hipStream_t stream) {
    const int*   tokens = (const int*)  d_in[0];
    const float* emb    = (const float*)d_in[1];
    const float* Wk     = (const float*)d_in[2];
    const float* Wr     = (const float*)d_in[3];
    const float* b      = (const float*)d_in[4];
    const float* Wd     = (const float*)d_in[5];
    const float* bd     = (const float*)d_in[6];
    float* out = (float*)d_out;
    (void)in_sizes; (void)n_in; (void)out_size;

    const size_t need = (size_t)VOCAB * EMB * sizeof(_Float16);   // 3.2 MB
    if (ws_size >= need) {
        _Float16* emb16 = (_Float16*)d_ws;
        build_emb16<<<dim3((VOCAB * EMB / 8 + 255) / 256), dim3(256), 0, stream>>>(
            emb, emb16);
        lstm_kernel<true><<<dim3(NBLK), dim3(1024), 0, stream>>>(
            tokens, emb, Wk, Wr, b, Wd, bd, emb16, out);
    } else {
        lstm_kernel<false><<<dim3(NBLK), dim3(1024), 0, stream>>>(
            tokens, emb, Wk, Wr, b, Wd, bd, nullptr, out);
    }
}

// Round 7
// 283.024 us; speedup vs baseline: 1.5918x; 1.5918x over previous
//
#include <hip/hip_runtime.h>

// R14: hit the MFMA-pipe floor. Per-block per-step the serial per-CU costs:
// MFMA pipe 48 instr/4 SIMD = 233 cyc (fixed, M=256 x K=96), LDS port,
// trans pipe. R13 died on redundant LDS reads (16 waves x 2 KB = 250+ cyc)
// + 8-way conflicts (144B pad -> stride 4 banks) + 16-wave skew. R14:
// 4 seqs/block, 128 blocks, 8 waves (2/SIMD, phases drift within barrier
// interval -> mutual latency hiding). Gates-in-M (m = 4*ulocal + gate),
// wave w = units [8w,8w+8) as 2 M-tiles -> 6 MFMA/wave (two 3-chains).
// C (col=l&15=seq, row=4q+reg) -> lane holds all 4 gates of one cell.
// DPP row_shl:4 moves tile1 cells to lanes 4<=n<8 -> ONE ACT pass/wave
// (10 trans). h rows 128 B, XOR-swizzle byte^=(seq&7)<<4 on write+read ->
// conflict-free b128 (each consec-8-lane group covers 8 distinct slots).
// x never in LDS: fp16 emb table (d_ws) per-lane 16 B load, 2-step
// prefetch; lgkm-only barrier keeps globals in flight. N=4-of-16 waste is
// FREE (wall = 512 x step; idle CUs are irrelevant).

#define VOCAB 50000
#define EMB 32
#define HID 64
#define NCLS 3
#define BATCH 512
#define TSEQ 512
#define FOURH 256
#define LOG2E 1.4426950408889634f
#define GSEQ 4
#define NBLK (BATCH / GSEQ)     // 128
#define BUFB 2048               // 16 rows x 128 B per buffer

typedef _Float16 half8 __attribute__((ext_vector_type(8)));
typedef float f32x4 __attribute__((ext_vector_type(4)));

#define MFMA16 __builtin_amdgcn_mfma_f32_16x16x32_f16
#define PKRTZ(a, b) __builtin_bit_cast(int, __builtin_amdgcn_cvt_pkrtz((a), (b)))

// LDS writes drained for cross-wave visibility; global loads stay in flight.
#define WAVE_BARRIER()                                        \
    {                                                         \
        asm volatile("s_waitcnt lgkmcnt(0)" ::: "memory");    \
        __builtin_amdgcn_s_barrier();                         \
    }

__device__ __forceinline__ float dpp_shl4(float x) {
    // row_shl:4 within each 16-lane row; lane j receives lane j-4.
    int y = __builtin_amdgcn_mov_dpp(__builtin_bit_cast(int, x), 0x104, 0xF, 0xF, true);
    return __builtin_bit_cast(float, y);
}

__global__ __launch_bounds__(256)
void build_emb16(const float* __restrict__ emb, _Float16* __restrict__ emb16) {
    const int idx = blockIdx.x * 256 + threadIdx.x;
    if (idx >= (VOCAB * EMB) / 8) return;
    const float4* src = (const float4*)(emb + (long)idx * 8);
    const float4 a = src[0], b = src[1];
    int4 o;
    o.x = PKRTZ(a.x, a.y);
    o.y = PKRTZ(a.z, a.w);
    o.z = PKRTZ(b.x, b.y);
    o.w = PKRTZ(b.z, b.w);
    ((int4*)emb16)[idx] = o;
}

// One step. CUR = buffer parity, TT = timestep. XR holds x(TT) (consumed,
// then refilled with x(TT+2) via token TKR); TKR refilled to token(TT+4).
#define LSTM_STEP(CUR, TT, XR, TKR)                                           \
    {                                                                         \
        const half8 b0 = *(const half8*)(hxc + (CUR) * BUFB + rb0);           \
        const half8 b1 = *(const half8*)(hxc + (CUR) * BUFB + rb1);           \
        const half8 xc = XR;                                                  \
        if (TAB) {                                                            \
            XR = *(const half8*)(emb16 + (long)TKR * EMB + (q << 3));         \
        } else {                                                              \
            const float4* xp = (const float4*)(emb + (long)TKR * EMB + (q << 3)); \
            const float4 xa = xp[0], xb = xp[1];                              \
            int4 pk;                                                          \
            pk.x = PKRTZ(xa.x, xa.y);                                         \
            pk.y = PKRTZ(xa.z, xa.w);                                         \
            pk.z = PKRTZ(xb.x, xb.y);                                         \
            pk.w = PKRTZ(xb.z, xb.w);                                         \
            XR = __builtin_bit_cast(half8, pk);                               \
        }                                                                     \
        const int tn4 = ((TT) + 4 < TSEQ) ? (TT) + 4 : TSEQ - 1;              \
        TKR = tp[tn4];                                                        \
        f32x4 acc0, acc1;                                                     \
        acc0 = MFMA16(wA[0][0], b0, zz, 0, 0, 0);                             \
        acc1 = MFMA16(wA[1][0], b0, zz, 0, 0, 0);                             \
        acc0 = MFMA16(wA[0][1], b1, acc0, 0, 0, 0);                           \
        acc1 = MFMA16(wA[1][1], b1, acc1, 0, 0, 0);                           \
        acc0 = MFMA16(wA[0][2], xc, acc0, 0, 0, 0);                           \
        acc1 = MFMA16(wA[1][2], xc, acc1, 0, 0, 0);                           \
        const float sh0 = dpp_shl4(acc1[0]);                                  \
        const float sh1 = dpp_shl4(acc1[1]);                                  \
        const float sh2 = dpp_shl4(acc1[2]);                                  \
        const float sh3 = dpp_shl4(acc1[3]);                                  \
        const float zi = low ? acc0[0] : sh0;                                 \
        const float zf = low ? acc0[1] : sh1;                                 \
        const float zg = low ? acc0[2] : sh2;                                 \
        const float zo = low ? acc0[3] : sh3;                                 \
        const float si = __builtin_amdgcn_rcpf(                               \
            1.0f + __builtin_amdgcn_exp2f(fmaf(zi, -LOG2E, bci)));            \
        const float sf = __builtin_amdgcn_rcpf(                               \
            1.0f + __builtin_amdgcn_exp2f(fmaf(zf, -LOG2E, bcf)));            \
        const float sg = __builtin_amdgcn_rcpf(                               \
            1.0f + __builtin_amdgcn_exp2f(fmaf(zg, -2.0f * LOG2E, bcg)));     \
        const float so = __builtin_amdgcn_rcpf(                               \
            1.0f + __builtin_amdgcn_exp2f(fmaf(zo, -LOG2E, bco)));            \
        const float gt = fmaf(2.0f, sg, -1.0f);                               \
        cst = fmaf(sf, cst, si * gt);                                         \
        const float st2 = __builtin_amdgcn_rcpf(                              \
            1.0f + __builtin_amdgcn_exp2f(cst * (-2.0f * LOG2E)));            \
        const float hv = so * fmaf(2.0f, st2, -1.0f);                         \
        if (n < 8) *(_Float16*)(hxc + ((CUR) ^ 1) * BUFB + waddr) = (_Float16)hv; \
        WAVE_BARRIER()                                                        \
    }

template <bool TAB>
__global__ __launch_bounds__(512)
void lstm_kernel(const int* __restrict__ tokens, const float* __restrict__ emb,
                 const float* __restrict__ Wk, const float* __restrict__ Wr,
                 const float* __restrict__ bias, const float* __restrict__ Wd,
                 const float* __restrict__ bd, const _Float16* __restrict__ emb16,
                 float* __restrict__ out)
{
    // [buf][row 0..15][64 halves]; rows 0..3 = live seqs, 4..15 stay zero.
    // Element h[s][k] lives at row-byte (2k) ^ ((s&7)<<4)  (XOR swizzle).
    __shared__ __align__(16) _Float16 hx[2][16][64];

    const int tid = threadIdx.x;
    const int w   = tid >> 6;          // wave 0..7 -> units [8w, 8w+8)
    const int l   = tid & 63;
    const int n   = l & 15;            // B/C col (seq); A row m
    const int q   = l >> 4;            // k-subchunk; C row group
    const bool low = (n < 4);
    const int s0  = blockIdx.x << 2;

    char* hxc = (char*)&hx[0][0][0];

    // ---- zero both buffers (4 KB) ----
    if (tid < 256) {
        int4 z4; z4.x = 0; z4.y = 0; z4.z = 0; z4.w = 0;
        ((int4*)hxc)[tid] = z4;
    }

    // ---- weight fragments: tile tau (M-tile T = 2w+tau), A[m][k]:
    //      m = n -> (ul = n>>2, gate = n&3); W col = 64*gate + 4T + ul.
    //      k = 32c + 8q + i; chunks 0,1 = Wr, chunk 2 = Wk. 24 VGPRs. ----
    half8 wA[2][3];
    {
        const int gate = n & 3;
        const int ul   = n >> 2;
#pragma unroll
        for (int tau = 0; tau < 2; ++tau) {
            const int col = (gate << 6) + (((w << 1) + tau) << 2) + ul;
#pragma unroll
            for (int i = 0; i < 8; ++i) {
                const int kq = (q << 3) + i;
                wA[tau][0][i] = (_Float16)Wr[kq * FOURH + col];
                wA[tau][1][i] = (_Float16)Wr[(32 + kq) * FOURH + col];
                wA[tau][2][i] = (_Float16)Wk[kq * FOURH + col];
            }
        }
    }

    // ---- consolidated cell for ACT: lanes n<8 own (seq = n&3,
    //      unit = 8w + (n&4) + q); n<4 from tile0, 4<=n<8 from tile1. ----
    const int uact = (w << 3) + (n & 4) + q;
    const int seqa = n & 3;
    const float bci = -bias[uact] * LOG2E;
    const float bcf = -bias[uact + 64] * LOG2E;
    const float bcg = -bias[uact + 128] * (2.0f * LOG2E);
    const float bco = -bias[uact + 192] * LOG2E;

    // ---- LDS byte offsets (swizzled) ----
    const int swzn = (n & 7) << 4;
    const int rb0  = n * 128 + ((q << 4) ^ swzn);          // h chunk 0
    const int rb1  = n * 128 + ((64 | (q << 4)) ^ swzn);   // h chunk 1
    const int waddr = seqa * 128 + ((uact << 1) ^ (seqa << 4));

    // ---- x pipeline: per-lane fp16 fragment, 2-step prefetch ----
    const int* tp = tokens + (long)(s0 + seqa) * TSEQ;
    half8 x0, x1;
    if (TAB) {
        x0 = *(const half8*)(emb16 + (long)tp[0] * EMB + (q << 3));
        x1 = *(const half8*)(emb16 + (long)tp[1] * EMB + (q << 3));
    } else {
        const float4* p0 = (const float4*)(emb + (long)tp[0] * EMB + (q << 3));
        const float4 a0 = p0[0], a1 = p0[1];
        int4 pk;
        pk.x = PKRTZ(a0.x, a0.y); pk.y = PKRTZ(a0.z, a0.w);
        pk.z = PKRTZ(a1.x, a1.y); pk.w = PKRTZ(a1.z, a1.w);
        x0 = __builtin_bit_cast(half8, pk);
        const float4* p1 = (const float4*)(emb + (long)tp[1] * EMB + (q << 3));
        const float4 b0 = p1[0], b1 = p1[1];
        pk.x = PKRTZ(b0.x, b0.y); pk.y = PKRTZ(b0.z, b0.w);
        pk.z = PKRTZ(b1.x, b1.y); pk.w = PKRTZ(b1.z, b1.w);
        x1 = __builtin_bit_cast(half8, pk);
    }
    int tkA = tp[2];
    int tkB = tp[3];

    __syncthreads();   // zeroed LDS visible

    float cst = 0.0f;
    const f32x4 zz = {0.0f, 0.0f, 0.0f, 0.0f};

    for (int t = 0; t < TSEQ; t += 2) {
        LSTM_STEP(0, t,     x0, tkA)
        LSTM_STEP(1, t + 1, x1, tkB)
    }

    // ---- epilogue: final h in buf 0 (swizzled). Dense(3) + softmax. ----
    if (tid < GSEQ) {
        float a0 = bd[0], a1 = bd[1], a2 = bd[2];
#pragma unroll 8
        for (int k = 0; k < HID; ++k) {
            const float hk = (float)*(const _Float16*)(
                hxc + tid * 128 + ((k << 1) ^ (tid << 4)));
            a0 = fmaf(hk, Wd[k * NCLS + 0], a0);
            a1 = fmaf(hk, Wd[k * NCLS + 1], a1);
            a2 = fmaf(hk, Wd[k * NCLS + 2], a2);
        }
        const float mm = fmaxf(a0, fmaxf(a1, a2));
        const float e0 = __expf(a0 - mm);
        const float e1 = __expf(a1 - mm);
        const float e2 = __expf(a2 - mm);
        const float den = e0 + e1 + e2;
        float* op = out + (s0 + tid) * NCLS;
        op[0] = e0 / den;
        op[1] = e1 / den;
        op[2] = e2 / den;
    }
}

extern "C" void kernel_launch(void* const* d_in, const int* in_sizes, int n_in,
                              void* d_out, int out_size, void* d_ws, size_t ws_size,
                              hipStream_t stream) {
    const int*   tokens = (const int*)  d_in[0];
    const float* emb    = (const float*)d_in[1];
    const float* Wk     = (const float*)d_in[2];
    const float* Wr     = (const float*)d_in[3];
    const float* b      = (const float*)d_in[4];
    const float* Wd     = (const float*)d_in[5];
    const float* bd     = (const float*)d_in[6];
    float* out = (float*)d_out;
    (void)in_sizes; (void)n_in; (void)out_size;

    const size_t need = (size_t)VOCAB * EMB * sizeof(_Float16);   // 3.2 MB
    if (ws_size >= need) {
        _Float16* emb16 = (_Float16*)d_ws;
        build_emb16<<<dim3((VOCAB * EMB / 8 + 255) / 256), dim3(256), 0, stream>>>(
            emb, emb16);
        lstm_kernel<true><<<dim3(NBLK), dim3(512), 0, stream>>>(
            tokens, emb, Wk, Wr, b, Wd, bd, emb16, out);
    } else {
        lstm_kernel<false><<<dim3(NBLK), dim3(512), 0, stream>>>(
            tokens, emb, Wk, Wr, b, Wd, bd, nullptr, out);
    }
}

// Round 9
// 201.319 us; speedup vs baseline: 2.2378x; 1.4058x over previous
//
#include <hip/hip_runtime.h>

// R16: R9b (170us, validated) + x-projection via MFMA C operand. R15 failed
// correctness bundling 3 new mechanisms; this keeps R9b's exact validated
// lane geometry and adds ONLY the table-C graft:
//   table2[v][4u+g] = emb[v]@Wk[:,64g+u] + bias[64g+u]  (f32, 51MB d_ws)
//   Lane (q,li) loads zx4 = table2[tok_q][4u..4u+3] (u = 16w+li) and passes
//   it UNCHANGED as C to all 4 gate MFMAs; since A-rows 4q+r are seq-q
//   replicas, reading acc_g[g] (row 4q+g) yields h_q@Wr[:,g,u] + zx4[g] --
//   gate-correct with zero shuffles/extra VALU.
// Effect: 12 -> 8 MFMA/wave (K 96->64), 3 -> 2 ds_read_b128, x-staging +
// PKRTZ deleted, zx in f32 (R8 numerics). zx4 prefetched 2 steps ahead;
// lgkm-only barriers keep the table loads in flight (~1200cyc cover for
// ~500cyc L3). !TAB fallback = R9b verbatim (K=96, x staged fp16 in LDS).

#define VOCAB 50000
#define EMB 32
#define HID 64
#define NCLS 3
#define BATCH 512
#define TSEQ 512
#define FOURH 256
#define LOG2E 1.4426950408889634f
#define GSEQ 4
#define NBLK (BATCH / GSEQ)

typedef _Float16 half8 __attribute__((ext_vector_type(8)));
typedef float f32x4 __attribute__((ext_vector_type(4)));

#define MFMA16 __builtin_amdgcn_mfma_f32_16x16x32_f16
#define PKRTZ(a, b) __builtin_bit_cast(int, __builtin_amdgcn_cvt_pkrtz((a), (b)))

// LDS writes drained for cross-wave visibility; global loads stay in flight.
#define WAVE_BARRIER()                                        \
    {                                                         \
        asm volatile("s_waitcnt lgkmcnt(0)" ::: "memory");    \
        __builtin_amdgcn_s_barrier();                         \
    }

// table[v][4u+g] = emb[v,:] @ Wk[:,64g+u] + bias[64g+u]  (gate-interleaved)
__global__ __launch_bounds__(256)
void build_table(const float* __restrict__ emb, const float* __restrict__ Wk,
                 const float* __restrict__ bias, float* __restrict__ table) {
    const int c = threadIdx.x;          // c = 4u + g
    const int u = c >> 2, g = c & 3;
    const int wi = (g << 6) + u;        // original W column
    const float bb = bias[wi];
    float wcol[EMB];
#pragma unroll
    for (int k = 0; k < EMB; ++k) wcol[k] = Wk[k * FOURH + wi];
    for (int v = blockIdx.x; v < VOCAB; v += gridDim.x) {
        const float4* er = (const float4*)(emb + (long)v * EMB);
        float acc = bb;
#pragma unroll
        for (int kk = 0; kk < EMB / 4; ++kk) {
            const float4 e = er[kk];
            acc = fmaf(e.x, wcol[kk * 4 + 0], acc);
            acc = fmaf(e.y, wcol[kk * 4 + 1], acc);
            acc = fmaf(e.z, wcol[kk * 4 + 2], acc);
            acc = fmaf(e.w, wcol[kk * 4 + 3], acc);
        }
        table[(long)v * FOURH + c] = acc;
    }
}

// One step. CUR = buffer parity, TT = timestep.
// TAB: ZX = C-preload (zx4 for token TT); refilled for TT+2 via TK
//      (= token TT+2); TK then refilled to token(TT+4) from LDS toks.
// !TAB: XW = f32 x(TT+1) regs (packed+stored to nxt buffer now);
//       XL receives x(TT+2). (R9b verbatim.)
#define LSTM_STEP(CUR, TT, ZX, TK, XW, XL)                                    \
    {                                                                         \
        const half8* ap = (const half8*)(hxc + (CUR) * 768 + abase);          \
        const half8 a0 = ap[0];                                               \
        const half8 a1 = ap[4];                                               \
        f32x4 ac0, ac1, ac2, ac3;                                             \
        if constexpr (TAB) {                                                  \
            ac0 = MFMA16(a0, bfr[0][0], ZX, 0, 0, 0);                         \
            ac1 = MFMA16(a0, bfr[1][0], ZX, 0, 0, 0);                         \
            ac2 = MFMA16(a0, bfr[2][0], ZX, 0, 0, 0);                         \
            ac3 = MFMA16(a0, bfr[3][0], ZX, 0, 0, 0);                         \
        } else {                                                              \
            ac0 = MFMA16(a0, bfr[0][0], zz, 0, 0, 0);                         \
            ac1 = MFMA16(a0, bfr[1][0], zz, 0, 0, 0);                         \
            ac2 = MFMA16(a0, bfr[2][0], zz, 0, 0, 0);                         \
            ac3 = MFMA16(a0, bfr[3][0], zz, 0, 0, 0);                         \
        }                                                                     \
        ac0 = MFMA16(a1, bfr[0][1], ac0, 0, 0, 0);                            \
        ac1 = MFMA16(a1, bfr[1][1], ac1, 0, 0, 0);                            \
        ac2 = MFMA16(a1, bfr[2][1], ac2, 0, 0, 0);                            \
        ac3 = MFMA16(a1, bfr[3][1], ac3, 0, 0, 0);                            \
        if constexpr (TAB) {                                                  \
            ZX = *(const f32x4*)(table + (long)(TK) * FOURH + (u << 2));      \
            const int tn4 = ((TT) + 4 < TSEQ) ? (TT) + 4 : TSEQ - 1;          \
            TK = toks[(q << 9) + tn4];                                        \
        } else {                                                              \
            const half8 a2 = ap[8];                                           \
            ac0 = MFMA16(a2, bfr[0][2], ac0, 0, 0, 0);                        \
            ac1 = MFMA16(a2, bfr[1][2], ac1, 0, 0, 0);                        \
            ac2 = MFMA16(a2, bfr[2][2], ac2, 0, 0, 0);                        \
            ac3 = MFMA16(a2, bfr[3][2], ac3, 0, 0, 0);                        \
            if (li8) {                                                        \
                int2 st;                                                      \
                st.x = PKRTZ(XW.x, XW.y);                                     \
                st.y = PKRTZ(XW.z, XW.w);                                     \
                *(int2*)(hxc + ((CUR) ^ 1) * 768 + xwoff) = st;               \
                const int tn2 = ((TT) + 2 < TSEQ) ? (TT) + 2 : TSEQ - 1;      \
                const int tk2 = toks[(w << 9) + tn2];                         \
                XL = *(const float4*)(emb + (long)tk2 * EMB + (l << 2));      \
            }                                                                 \
        }                                                                     \
        const float zi = ac0[0];                                              \
        const float zf = ac1[1];                                              \
        const float zg = ac2[2];                                              \
        const float zo = ac3[3];                                              \
        const float si = __builtin_amdgcn_rcpf(                               \
            1.0f + __builtin_amdgcn_exp2f(fmaf(zi, -LOG2E, bci)));            \
        const float sf = __builtin_amdgcn_rcpf(                               \
            1.0f + __builtin_amdgcn_exp2f(fmaf(zf, -LOG2E, bcf)));            \
        const float sg = __builtin_amdgcn_rcpf(                               \
            1.0f + __builtin_amdgcn_exp2f(fmaf(zg, -2.0f * LOG2E, bcg)));     \
        const float so = __builtin_amdgcn_rcpf(                               \
            1.0f + __builtin_amdgcn_exp2f(fmaf(zo, -LOG2E, bco)));            \
        const float gt = fmaf(2.0f, sg, -1.0f);                               \
        cst = fmaf(sf, cst, si * gt);                                         \
        const float st2 = __builtin_amdgcn_rcpf(                              \
            1.0f + __builtin_amdgcn_exp2f(cst * (-2.0f * LOG2E)));            \
        const float hv = so * fmaf(2.0f, st2, -1.0f);                         \
        *(_Float16*)(hxc + ((CUR) ^ 1) * 768 + hwoff) = (_Float16)hv;         \
        WAVE_BARRIER()                                                        \
    }

template <bool TAB>
__global__ __launch_bounds__(256)
void lstm_kernel(const int* __restrict__ tokens, const float* __restrict__ emb,
                 const float* __restrict__ Wk, const float* __restrict__ Wr,
                 const float* __restrict__ bias, const float* __restrict__ Wd,
                 const float* __restrict__ bd, const float* __restrict__ table,
                 float* __restrict__ out)
{
    // [buf][seq][k]: k 0..63 = h (fp16); k 64..95 = x (fp16, !TAB only).
    __shared__ __align__(16) _Float16 hx[2][GSEQ][96];
    __shared__ int toks[GSEQ * TSEQ];

    const int tid = threadIdx.x;
    const int w   = tid >> 6;          // wave 0..3 -> units [16w, 16w+16)
    const int l   = tid & 63;
    const int li  = l & 15;
    const int q   = l >> 4;            // seq id (C reg0 row-group); k-subchunk
    const bool li8 = (l < 8);
    const int s0  = blockIdx.x << 2;

    char* hxc = (char*)&hx[0][0][0];

    // ---- stage all 2048 tokens (8 KB contiguous) ----
    {
        const int4* src = (const int4*)(tokens + ((long)s0 << 9));
        int4* dst = (int4*)toks;
        dst[tid]       = src[tid];
        dst[tid + 256] = src[tid + 256];
    }

    // ---- zero h-region of buffer 0 (4 rows x 128 B) ----
    if (tid < 64) {
        int2 z2; z2.x = 0; z2.y = 0;
        *(int2*)(hxc + (tid >> 4) * 192 + ((tid & 15) << 3)) = z2;
    }

    // ---- weight fragments (R9b verbatim): B[k, col], col = 64g + 16w + li,
    //      k = 32*c2 + 8q + i. Chunks 0,1 = Wr; chunk 2 (Wk) only !TAB. ----
    half8 bfr[4][3];
#pragma unroll
    for (int g = 0; g < 4; ++g) {
        const int col = (g << 6) + (w << 4) + li;
#pragma unroll
        for (int i = 0; i < 8; ++i) {
            const int kq = (q << 3) + i;
            bfr[g][0][i] = (_Float16)Wr[kq * FOURH + col];
            bfr[g][1][i] = (_Float16)Wr[(32 + kq) * FOURH + col];
            if constexpr (!TAB) bfr[g][2][i] = (_Float16)Wk[kq * FOURH + col];
        }
    }

    // ---- activation constants: bias in table under TAB ----
    const int u = (w << 4) + li;       // this lane's hidden unit
    const float bci = TAB ? 0.0f : -bias[u] * LOG2E;
    const float bcf = TAB ? 0.0f : -bias[u + 64] * LOG2E;
    const float bcg = TAB ? 0.0f : -bias[u + 128] * (2.0f * LOG2E);
    const float bco = TAB ? 0.0f : -bias[u + 192] * LOG2E;

    // ---- per-lane LDS byte offsets (R9b verbatim) ----
    const int abase = ((li >> 2) * 192) + (q << 4);   // A-frag base (row bcast)
    const int hwoff = q * 192 + (u << 1);             // h write: [seq=q][u]
    const int xwoff = w * 192 + 128 + (l << 3);       // x write (!TAB)

    __syncthreads();   // toks + zeroed h visible

    // ---- prologue: zx/x pipeline primed 2 steps ahead ----
    f32x4 zxA{}, zxB{};
    int tkA = 0, tkB = 0;
    float4 xA = make_float4(0.f, 0.f, 0.f, 0.f);
    float4 xB = make_float4(0.f, 0.f, 0.f, 0.f);
    if constexpr (TAB) {
        const int t0 = toks[(q << 9) + 0];
        const int t1 = toks[(q << 9) + 1];
        zxA = *(const f32x4*)(table + (long)t0 * FOURH + (u << 2));
        zxB = *(const f32x4*)(table + (long)t1 * FOURH + (u << 2));
        tkA = toks[(q << 9) + 2];
        tkB = toks[(q << 9) + 3];
    } else {
        if (li8) {
            const int tk0 = toks[w << 9];
            const float4 x0 = *(const float4*)(emb + (long)tk0 * EMB + (l << 2));
            int2 st;
            st.x = PKRTZ(x0.x, x0.y);
            st.y = PKRTZ(x0.z, x0.w);
            *(int2*)(hxc + xwoff) = st;
            const int tk1 = toks[(w << 9) + 1];
            xA = *(const float4*)(emb + (long)tk1 * EMB + (l << 2));
        }
    }
    __syncthreads();

    float cst = 0.0f;
    const f32x4 zz = {0.0f, 0.0f, 0.0f, 0.0f};

    for (int t = 0; t < TSEQ; t += 2) {
        LSTM_STEP(0, t,     zxA, tkA, xA, xB)
        LSTM_STEP(1, t + 1, zxB, tkB, xB, xA)
    }

    // ---- epilogue: final h in buf 0 (T even). Dense(3) + softmax. ----
    if (tid < GSEQ) {
        const _Float16* hf = &hx[0][tid][0];
        float a0 = bd[0], a1 = bd[1], a2 = bd[2];
#pragma unroll 8
        for (int k = 0; k < HID; ++k) {
            const float hk = (float)hf[k];
            a0 = fmaf(hk, Wd[k * NCLS + 0], a0);
            a1 = fmaf(hk, Wd[k * NCLS + 1], a1);
            a2 = fmaf(hk, Wd[k * NCLS + 2], a2);
        }
        const float mm = fmaxf(a0, fmaxf(a1, a2));
        const float e0 = __expf(a0 - mm);
        const float e1 = __expf(a1 - mm);
        const float e2 = __expf(a2 - mm);
        const float den = e0 + e1 + e2;
        float* op = out + (s0 + tid) * NCLS;
        op[0] = e0 / den;
        op[1] = e1 / den;
        op[2] = e2 / den;
    }
}

extern "C" void kernel_launch(void* const* d_in, const int* in_sizes, int n_in,
                              void* d_out, int out_size, void* d_ws, size_t ws_size,
                              hipStream_t stream) {
    const int*   tokens = (const int*)  d_in[0];
    const float* emb    = (const float*)d_in[1];
    const float* Wk     = (const float*)d_in[2];
    const float* Wr     = (const float*)d_in[3];
    const float* b      = (const float*)d_in[4];
    const float* Wd     = (const float*)d_in[5];
    const float* bd     = (const float*)d_in[6];
    float* out = (float*)d_out;
    (void)in_sizes; (void)n_in; (void)out_size;

    const size_t need = (size_t)VOCAB * FOURH * sizeof(float);   // 51.2 MB
    if (ws_size >= need) {
        float* table = (float*)d_ws;
        build_table<<<dim3(2048), dim3(256), 0, stream>>>(emb, Wk, b, table);
        lstm_kernel<true><<<dim3(NBLK), dim3(256), 0, stream>>>(
            tokens, emb, Wk, Wr, b, Wd, bd, table, out);
    } else {
        lstm_kernel<false><<<dim3(NBLK), dim3(256), 0, stream>>>(
            tokens, emb, Wk, Wr, b, Wd, bd, nullptr, out);
    }
}